// Round 2
// baseline (147.937 us; speedup 1.0000x reference)
//
#include <hip/hip_runtime.h>

typedef __attribute__((ext_vector_type(8))) short short8;
typedef __attribute__((ext_vector_type(4))) float floatx4;

#define LEAKY 0.2f
#define NEGM -9e15f

// --- bf16 helpers (RNE, finite inputs) ---
__device__ __forceinline__ unsigned short f2bf(float f) {
  unsigned int u = __float_as_uint(f);
  u = u + 0x7FFFu + ((u >> 16) & 1u);
  return (unsigned short)(u >> 16);
}
__device__ __forceinline__ float bf2f(short s) {
  return __uint_as_float(((unsigned int)(unsigned short)s) << 16);
}

// ---------------------------------------------------------------------------
// Prep (unchanged, known-good): h fp32 -> Hsw (row-major bf16, row-XOR baked)
//                                      -> HTsw (transposed bf16, row-XOR baked)
// ---------------------------------------------------------------------------
__global__ __launch_bounds__(256) void prep_kernel(
    const float* __restrict__ h, unsigned short* __restrict__ Hsw,
    unsigned short* __restrict__ HTsw) {
  const int b = blockIdx.x >> 2, q = blockIdx.x & 3;
  const int t = threadIdx.x;
  const float* hb = h + b * 65536;
  unsigned short* Hb = Hsw + b * 65536;
  unsigned short* HTb = HTsw + b * 65536;
#pragma unroll
  for (int j = 0; j < 8; ++j) {
    int c = t + j * 256;
    int m = 64 * q + (c >> 5);
    int d0 = (c & 31) * 8;
    const float4* src = (const float4*)(hb + m * 256 + d0);
    float4 x = src[0], y = src[1];
    short8 v;
    v[0] = (short)f2bf(x.x); v[1] = (short)f2bf(x.y);
    v[2] = (short)f2bf(x.z); v[3] = (short)f2bf(x.w);
    v[4] = (short)f2bf(y.x); v[5] = (short)f2bf(y.y);
    v[6] = (short)f2bf(y.z); v[7] = (short)f2bf(y.w);
    *(short8*)(Hb + m * 256 + (d0 ^ ((m & 7) << 3))) = v;
  }
#pragma unroll
  for (int j = 0; j < 8; ++j) {
    int p = t + j * 256;
    int d = 64 * q + (p & 63);
    int m0 = (p >> 6) * 8;
    short8 v;
#pragma unroll
    for (int jj = 0; jj < 8; ++jj) v[jj] = (short)f2bf(hb[(m0 + jj) * 256 + d]);
    *(short8*)(HTb + d * 256 + (m0 ^ ((d & 7) << 3))) = v;
  }
}

// Stage a PAIR of 16 KB tiles (32 rows x 512 B each): waves 0-3 -> tile0,
// waves 4-7 -> tile1. Linear LDS dest (wave-uniform base), width=16.
__device__ __forceinline__ void stage_pair(const unsigned short* g0,
                                           const unsigned short* g1,
                                           unsigned char* s0, unsigned char* s1,
                                           int w, int l) {
  const unsigned char* gsrc = (w < 4) ? (const unsigned char*)g0 : (const unsigned char*)g1;
  unsigned char* ldst = (w < 4) ? s0 : s1;
  const int wo = (w & 3) * 4096;
#pragma unroll
  for (int i = 0; i < 4; ++i) {
    const int off = wo + i * 1024;
    __builtin_amdgcn_global_load_lds(
        (const __attribute__((address_space(1))) unsigned int*)(gsrc + off + l * 16),
        (__attribute__((address_space(3))) unsigned int*)(ldst + off), 16, 0, 0);
  }
}

// ---------------------------------------------------------------------------
// Fused v2: block = (b, 64 n-rows), 512 threads = 8 waves.
// wave w: rw = w&3 (16-row group), mh = w>>2 (m- or d-half of 128).
// Pair-staging keeps all 8 waves computing every iteration; 2 waves/SIMD.
// LDS: [0,32K) A then alpha; [32K,96K) B tile-pair double buffer;
//      [96K,100K) a fp32; [100K,100.5K) pmax; [100.5K,101K) psum/psq.
// ---------------------------------------------------------------------------
__global__ __launch_bounds__(512, 2) void fused_kernel(
    const float* __restrict__ h, const int* __restrict__ adj,
    const float* __restrict__ a, float* __restrict__ out,
    const unsigned short* __restrict__ Hsw, const unsigned short* __restrict__ HTsw) {
  __shared__ __align__(16) unsigned char lds[103424];
  unsigned short* ldsU = (unsigned short*)lds;
  unsigned char* Bbase = lds + 32768;
  float* aLds = (float*)(lds + 98304);
  float* pmax = (float*)(lds + 102400);  // [64][2]
  float* psum = (float*)(lds + 102912);  // [64][2] (reused as psq)

  const int tid = threadIdx.x;
  const int w = tid >> 6, l = tid & 63;
  const int l16 = l & 15, lhi = l >> 4;
  const int rw = w & 3, mh = w >> 2;
  // XCD swizzle: 4 blocks of same b co-resident on one XCD (grid 256)
  const int id = blockIdx.x;
  const int b = (id & 7) + 8 * (id >> 5);
  const int n0 = ((id >> 3) & 3) * 64;

  const float* hb = h + b * 65536;
  const int* adjb = adj + b * 65536;
  const unsigned short* HswB = Hsw + b * 65536;
  const unsigned short* HTswB = HTsw + b * 65536;

  // prologue: stage phase-1 pair 0 (tiles m:0..31 and m:128..159)
  stage_pair(HswB, HswB + 4 * 32 * 256, Bbase, Bbase + 16384, w, l);

  // stage A rows (n0..n0+63) fp32 -> bf16 swizzled into [0,32K)
#pragma unroll
  for (int j = 0; j < 4; ++j) {
    int c = tid + j * 512;            // 0..2047
    int r = c >> 5;                   // 0..63
    int d0 = (c & 31) * 8;
    const float4* src = (const float4*)(hb + (n0 + r) * 256 + d0);
    float4 x = src[0], y = src[1];
    short8 v;
    v[0] = (short)f2bf(x.x); v[1] = (short)f2bf(x.y);
    v[2] = (short)f2bf(x.z); v[3] = (short)f2bf(x.w);
    v[4] = (short)f2bf(y.x); v[5] = (short)f2bf(y.y);
    v[6] = (short)f2bf(y.z); v[7] = (short)f2bf(y.w);
    *(short8*)(ldsU + r * 256 + (d0 ^ ((r & 7) << 3))) = v;
  }
  if (tid < 256) ((float4*)aLds)[tid] = ((const float4*)a)[tid];
  __syncthreads();  // A + a ready; pair 0 staged (vmcnt drained)

  // A_k = bf16(h * a_k) in regs: rows rw*16+l16, 8 K-steps, 4 k's (128 VGPR)
  short8 Ak[4][8];
  const int arow = rw * 16 + l16;
  {
#pragma unroll
    for (int ks = 0; ks < 8; ++ks) {
      int d0 = ks * 32 + lhi * 8;
      short8 hv = *(const short8*)(ldsU + arow * 256 + (d0 ^ ((arow & 7) << 3)));
      float hf[8];
#pragma unroll
      for (int jj = 0; jj < 8; ++jj) hf[jj] = bf2f(hv[jj]);
#pragma unroll
      for (int k = 0; k < 4; ++k) {
        const float4* a4 = (const float4*)(aLds + k * 256 + d0);
        float4 p = a4[0], qv = a4[1];
        short8 o;
        o[0] = (short)f2bf(hf[0] * p.x);  o[1] = (short)f2bf(hf[1] * p.y);
        o[2] = (short)f2bf(hf[2] * p.z);  o[3] = (short)f2bf(hf[3] * p.w);
        o[4] = (short)f2bf(hf[4] * qv.x); o[5] = (short)f2bf(hf[5] * qv.y);
        o[6] = (short)f2bf(hf[6] * qv.z); o[7] = (short)f2bf(hf[7] * qv.w);
        Ak[k][ks] = o;
      }
    }
  }

  // ---- Phase 1: 4 iterations, each = one tile-pair; wave uses half mh ----
  floatx4 logits[8];
  const int* adjrow = adjb + (n0 + rw * 16 + lhi * 4) * 256;
#pragma unroll
  for (int it = 0; it < 4; ++it) {
    const int cur = it & 1;
    if (it < 3)
      stage_pair(HswB + (it + 1) * 32 * 256, HswB + (it + 5) * 32 * 256,
                 Bbase + (1 - cur) * 32768, Bbase + (1 - cur) * 32768 + 16384, w, l);
    int adjv[2][4];
#pragma unroll
    for (int cf = 0; cf < 2; ++cf)
#pragma unroll
      for (int r = 0; r < 4; ++r)
        adjv[cf][r] = adjrow[r * 256 + mh * 128 + it * 32 + cf * 16 + l16];
    floatx4 acc[2][4];
#pragma unroll
    for (int cf = 0; cf < 2; ++cf)
#pragma unroll
      for (int k = 0; k < 4; ++k) {
        floatx4 z = {0.f, 0.f, 0.f, 0.f};
        acc[cf][k] = z;
      }
    const unsigned short* Bt = (const unsigned short*)(Bbase + cur * 32768 + mh * 16384);
#pragma unroll
    for (int ks = 0; ks < 8; ++ks) {
      int d0 = ks * 32 + lhi * 8;
      short8 b0 = *(const short8*)(Bt + l16 * 256 + (d0 ^ ((l16 & 7) << 3)));
      short8 b1 = *(const short8*)(Bt + (16 + l16) * 256 + (d0 ^ ((l16 & 7) << 3)));
#pragma unroll
      for (int k = 0; k < 4; ++k) {
        acc[0][k] = __builtin_amdgcn_mfma_f32_16x16x32_bf16(Ak[k][ks], b0, acc[0][k], 0, 0, 0);
        acc[1][k] = __builtin_amdgcn_mfma_f32_16x16x32_bf16(Ak[k][ks], b1, acc[1][k], 0, 0, 0);
      }
    }
#pragma unroll
    for (int cf = 0; cf < 2; ++cf) {
      floatx4 L;
#pragma unroll
      for (int r = 0; r < 4; ++r) {
        int av = adjv[cf][r];
        float s = NEGM;
        s = (av == 1) ? acc[cf][0][r] : s;
        s = (av == 2) ? acc[cf][1][r] : s;
        s = (av == 3) ? acc[cf][2][r] : s;
        s = (av == 4) ? acc[cf][3][r] : s;
        s = (s > 0.f) ? s : LEAKY * s;
        L[r] = s;
      }
      logits[it * 2 + cf] = L;
    }
    __syncthreads();
  }

  // issue phase-2 pair 0 (HT tiles d:0..31 and d:128..159); overlaps softmax
  stage_pair(HTswB, HTswB + 4 * 32 * 256, Bbase, Bbase + 16384, w, l);

  // ---- softmax across both m-halves via LDS partials ----
  const int row0 = rw * 16 + lhi * 4;
  float mloc[4];
#pragma unroll
  for (int r = 0; r < 4; ++r) {
    float m = logits[0][r];
#pragma unroll
    for (int f = 1; f < 8; ++f) m = fmaxf(m, logits[f][r]);
#pragma unroll
    for (int s = 1; s < 16; s <<= 1) m = fmaxf(m, __shfl_xor(m, s));
    mloc[r] = m;
    if (l16 == 0) pmax[(row0 + r) * 2 + mh] = m;
  }
  __syncthreads();
  float sm[4];
#pragma unroll
  for (int r = 0; r < 4; ++r) {
    float gm = fmaxf(pmax[(row0 + r) * 2], pmax[(row0 + r) * 2 + 1]);
    float s = 0.f;
#pragma unroll
    for (int f = 0; f < 8; ++f) {
      float e = __expf(logits[f][r] - gm);
      logits[f][r] = e;
      s += e;
    }
#pragma unroll
    for (int sh = 1; sh < 16; sh <<= 1) s += __shfl_xor(s, sh);
    sm[r] = s;
    if (l16 == 0) psum[(row0 + r) * 2 + mh] = s;
  }
  __syncthreads();
  float inv[4];
#pragma unroll
  for (int r = 0; r < 4; ++r)
    inv[r] = 1.f / (psum[(row0 + r) * 2] + psum[(row0 + r) * 2 + 1]);
  (void)mloc; (void)sm;
  // alpha bf16 swizzled into A-region: row, col m = mh*128 + f*16 + l16
#pragma unroll
  for (int f = 0; f < 8; ++f)
#pragma unroll
    for (int r = 0; r < 4; ++r) {
      int row = row0 + r;
      int mcol = mh * 128 + f * 16 + l16;
      ldsU[row * 256 + (mcol ^ ((row & 7) << 3))] = f2bf(logits[f][r] * inv[r]);
    }
  __syncthreads();

  // ---- Phase 2: out = alpha @ H; wave covers [16 rows][128 d (half mh)] ----
  short8 af[8];
#pragma unroll
  for (int ks = 0; ks < 8; ++ks) {
    int m0 = ks * 32 + lhi * 8;
    af[ks] = *(const short8*)(ldsU + arow * 256 + (m0 ^ ((arow & 7) << 3)));
  }
  floatx4 oa[8];
#pragma unroll
  for (int f = 0; f < 8; ++f) {
    floatx4 z = {0.f, 0.f, 0.f, 0.f};
    oa[f] = z;
  }
#pragma unroll
  for (int it = 0; it < 4; ++it) {
    const int cur = it & 1;
    if (it < 3)
      stage_pair(HTswB + (it + 1) * 32 * 256, HTswB + (it + 5) * 32 * 256,
                 Bbase + (1 - cur) * 32768, Bbase + (1 - cur) * 32768 + 16384, w, l);
    const unsigned short* Bt = (const unsigned short*)(Bbase + cur * 32768 + mh * 16384);
#pragma unroll
    for (int cf = 0; cf < 2; ++cf)
#pragma unroll
      for (int ks = 0; ks < 8; ++ks) {
        int m0 = ks * 32 + lhi * 8;
        short8 bf = *(const short8*)(Bt + (cf * 16 + l16) * 256 + (m0 ^ ((l16 & 7) << 3)));
        oa[it * 2 + cf] = __builtin_amdgcn_mfma_f32_16x16x32_bf16(af[ks], bf, oa[it * 2 + cf], 0, 0, 0);
      }
    __syncthreads();
  }

  // ---- epilogue: L2 normalize (cross d-half combine) + residual ----
  float ssq[4] = {0.f, 0.f, 0.f, 0.f};
#pragma unroll
  for (int f = 0; f < 8; ++f)
#pragma unroll
    for (int r = 0; r < 4; ++r) ssq[r] += oa[f][r] * oa[f][r];
#pragma unroll
  for (int r = 0; r < 4; ++r) {
#pragma unroll
    for (int s = 1; s < 16; s <<= 1) ssq[r] += __shfl_xor(ssq[r], s);
    if (l16 == 0) psum[(row0 + r) * 2 + mh] = ssq[r];
  }
  __syncthreads();
  float innv[4];
#pragma unroll
  for (int r = 0; r < 4; ++r) {
    float tot = psum[(row0 + r) * 2] + psum[(row0 + r) * 2 + 1];
    innv[r] = 1.f / fmaxf(sqrtf(tot), 1e-12f);
  }
  float* ob = out + b * 65536;
#pragma unroll
  for (int f = 0; f < 8; ++f)
#pragma unroll
    for (int r = 0; r < 4; ++r) {
      int n = n0 + row0 + r;
      int d = mh * 128 + f * 16 + l16;
      ob[n * 256 + d] = oa[f][r] * innv[r] + hb[n * 256 + d];
    }
}

extern "C" void kernel_launch(void* const* d_in, const int* in_sizes, int n_in,
                              void* d_out, int out_size, void* d_ws, size_t ws_size,
                              hipStream_t stream) {
  const float* h = (const float*)d_in[0];
  const int* adj = (const int*)d_in[1];
  const float* a = (const float*)d_in[2];
  float* out = (float*)d_out;
  unsigned short* Hsw = (unsigned short*)d_ws;
  unsigned short* HTsw = Hsw + 64 * 256 * 256;
  prep_kernel<<<256, 256, 0, stream>>>(h, Hsw, HTsw);
  fused_kernel<<<256, 512, 0, stream>>>(h, adj, a, out, Hsw, HTsw);
}

// Round 4
// 147.877 us; speedup vs baseline: 1.0004x; 1.0004x over previous
//
#include <hip/hip_runtime.h>

typedef __attribute__((ext_vector_type(8))) short short8;
typedef __attribute__((ext_vector_type(4))) float floatx4;

#define LEAKY 0.2f
#define NEGM -9e15f

// --- bf16 helpers (RNE, finite inputs) ---
__device__ __forceinline__ unsigned short f2bf(float f) {
  unsigned int u = __float_as_uint(f);
  u = u + 0x7FFFu + ((u >> 16) & 1u);
  return (unsigned short)(u >> 16);
}
__device__ __forceinline__ float bf2f(short s) {
  return __uint_as_float(((unsigned int)(unsigned short)s) << 16);
}

// ---------------------------------------------------------------------------
// Prep (unchanged, known-good): h fp32 -> Hsw (row-major bf16, row-XOR baked)
//                                      -> HTsw (transposed bf16, row-XOR baked)
// ---------------------------------------------------------------------------
__global__ __launch_bounds__(256) void prep_kernel(
    const float* __restrict__ h, unsigned short* __restrict__ Hsw,
    unsigned short* __restrict__ HTsw) {
  const int b = blockIdx.x >> 2, q = blockIdx.x & 3;
  const int t = threadIdx.x;
  const float* hb = h + b * 65536;
  unsigned short* Hb = Hsw + b * 65536;
  unsigned short* HTb = HTsw + b * 65536;
#pragma unroll
  for (int j = 0; j < 8; ++j) {
    int c = t + j * 256;
    int m = 64 * q + (c >> 5);
    int d0 = (c & 31) * 8;
    const float4* src = (const float4*)(hb + m * 256 + d0);
    float4 x = src[0], y = src[1];
    short8 v;
    v[0] = (short)f2bf(x.x); v[1] = (short)f2bf(x.y);
    v[2] = (short)f2bf(x.z); v[3] = (short)f2bf(x.w);
    v[4] = (short)f2bf(y.x); v[5] = (short)f2bf(y.y);
    v[6] = (short)f2bf(y.z); v[7] = (short)f2bf(y.w);
    *(short8*)(Hb + m * 256 + (d0 ^ ((m & 7) << 3))) = v;
  }
#pragma unroll
  for (int j = 0; j < 8; ++j) {
    int p = t + j * 256;
    int d = 64 * q + (p & 63);
    int m0 = (p >> 6) * 8;
    short8 v;
#pragma unroll
    for (int jj = 0; jj < 8; ++jj) v[jj] = (short)f2bf(hb[(m0 + jj) * 256 + d]);
    *(short8*)(HTb + d * 256 + (m0 ^ ((d & 7) << 3))) = v;
  }
}

// Stage a PAIR of 16 KB tiles (32 rows x 512 B each): waves 0-3 -> tile0,
// waves 4-7 -> tile1. Linear LDS dest (wave-uniform base), width=16.
__device__ __forceinline__ void stage_pair(const unsigned short* g0,
                                           const unsigned short* g1,
                                           unsigned char* s0, unsigned char* s1,
                                           int w, int l) {
  const unsigned char* gsrc = (w < 4) ? (const unsigned char*)g0 : (const unsigned char*)g1;
  unsigned char* ldst = (w < 4) ? s0 : s1;
  const int wo = (w & 3) * 4096;
#pragma unroll
  for (int i = 0; i < 4; ++i) {
    const int off = wo + i * 1024;
    __builtin_amdgcn_global_load_lds(
        (const __attribute__((address_space(1))) unsigned int*)(gsrc + off + l * 16),
        (__attribute__((address_space(3))) unsigned int*)(ldst + off), 16, 0, 0);
  }
}

// ---------------------------------------------------------------------------
// Fused v3: block = (b, 64 n-rows), 512 threads = 8 waves.
// wave w: rw = w&3 (16-row group), mh = w>>2 (m- or d-half of 128).
// amdgpu_waves_per_eu(2,2) pins the register budget at 256 VGPR (v2's
// launch_bounds(512,2) let the compiler target 128 VGPR -> ~180 reg spill,
// 95 MB of scratch writes, 74 us).
// LDS: [0,32K) A then alpha; [32K,96K) B tile-pair double buffer;
//      [96K,100K) a fp32; [100K,100.5K) pmax; [100.5K,101K) psum/psq.
// ---------------------------------------------------------------------------
__global__ __launch_bounds__(512)
__attribute__((amdgpu_waves_per_eu(2, 2))) void fused_kernel(
    const float* __restrict__ h, const int* __restrict__ adj,
    const float* __restrict__ a, float* __restrict__ out,
    const unsigned short* __restrict__ Hsw, const unsigned short* __restrict__ HTsw) {
  __shared__ __align__(16) unsigned char lds[103424];
  unsigned short* ldsU = (unsigned short*)lds;
  unsigned char* Bbase = lds + 32768;
  float* aLds = (float*)(lds + 98304);
  float* pmax = (float*)(lds + 102400);  // [64][2]
  float* psum = (float*)(lds + 102912);  // [64][2] (reused as psq)

  const int tid = threadIdx.x;
  const int w = tid >> 6, l = tid & 63;
  const int l16 = l & 15, lhi = l >> 4;
  const int rw = w & 3, mh = w >> 2;
  // XCD swizzle: 4 blocks of same b co-resident on one XCD (grid 256)
  const int id = blockIdx.x;
  const int b = (id & 7) + 8 * (id >> 5);
  const int n0 = ((id >> 3) & 3) * 64;

  const float* hb = h + b * 65536;
  const int* adjb = adj + b * 65536;
  const unsigned short* HswB = Hsw + b * 65536;
  const unsigned short* HTswB = HTsw + b * 65536;

  // prologue: stage phase-1 pair 0 (tiles m:0..31 and m:128..159)
  stage_pair(HswB, HswB + 4 * 32 * 256, Bbase, Bbase + 16384, w, l);

  // stage A rows (n0..n0+63) straight from Hsw (already bf16 + row-swizzled;
  // n0 % 64 == 0 so baked (row&7) swizzle == local swizzle). 32 KB linear.
  {
    const unsigned char* asrc = (const unsigned char*)(HswB + n0 * 256);
#pragma unroll
    for (int i = 0; i < 4; ++i) {
      const int off = i * 8192 + w * 1024;
      __builtin_amdgcn_global_load_lds(
          (const __attribute__((address_space(1))) unsigned int*)(asrc + off + l * 16),
          (__attribute__((address_space(3))) unsigned int*)(lds + off), 16, 0, 0);
    }
  }
  if (tid < 256) ((float4*)aLds)[tid] = ((const float4*)a)[tid];
  __syncthreads();  // A + a + pair 0 ready (barrier drains vmcnt)

  // A_k = bf16(h * a_k) in regs: rows rw*16+l16, 8 K-steps, 4 k's (128 VGPR)
  short8 Ak[4][8];
  const int arow = rw * 16 + l16;
  {
#pragma unroll
    for (int ks = 0; ks < 8; ++ks) {
      int d0 = ks * 32 + lhi * 8;
      short8 hv = *(const short8*)(ldsU + arow * 256 + (d0 ^ ((arow & 7) << 3)));
      float hf[8];
#pragma unroll
      for (int jj = 0; jj < 8; ++jj) hf[jj] = bf2f(hv[jj]);
#pragma unroll
      for (int k = 0; k < 4; ++k) {
        const float4* a4 = (const float4*)(aLds + k * 256 + d0);
        float4 p = a4[0], qv = a4[1];
        short8 o;
        o[0] = (short)f2bf(hf[0] * p.x);  o[1] = (short)f2bf(hf[1] * p.y);
        o[2] = (short)f2bf(hf[2] * p.z);  o[3] = (short)f2bf(hf[3] * p.w);
        o[4] = (short)f2bf(hf[4] * qv.x); o[5] = (short)f2bf(hf[5] * qv.y);
        o[6] = (short)f2bf(hf[6] * qv.z); o[7] = (short)f2bf(hf[7] * qv.w);
        Ak[k][ks] = o;
      }
    }
  }

  // ---- Phase 1: 4 iterations, each = one tile-pair; wave uses half mh ----
  floatx4 logits[8];
  const int* adjrow = adjb + (n0 + rw * 16 + lhi * 4) * 256;
#pragma unroll
  for (int it = 0; it < 4; ++it) {
    const int cur = it & 1;
    if (it < 3)
      stage_pair(HswB + (it + 1) * 32 * 256, HswB + (it + 5) * 32 * 256,
                 Bbase + (1 - cur) * 32768, Bbase + (1 - cur) * 32768 + 16384, w, l);
    int adjv[2][4];
#pragma unroll
    for (int cf = 0; cf < 2; ++cf)
#pragma unroll
      for (int r = 0; r < 4; ++r)
        adjv[cf][r] = adjrow[r * 256 + mh * 128 + it * 32 + cf * 16 + l16];
    floatx4 acc[2][4];
#pragma unroll
    for (int cf = 0; cf < 2; ++cf)
#pragma unroll
      for (int k = 0; k < 4; ++k) {
        floatx4 z = {0.f, 0.f, 0.f, 0.f};
        acc[cf][k] = z;
      }
    const unsigned short* Bt = (const unsigned short*)(Bbase + cur * 32768 + mh * 16384);
#pragma unroll
    for (int ks = 0; ks < 8; ++ks) {
      int d0 = ks * 32 + lhi * 8;
      short8 b0 = *(const short8*)(Bt + l16 * 256 + (d0 ^ ((l16 & 7) << 3)));
      short8 b1 = *(const short8*)(Bt + (16 + l16) * 256 + (d0 ^ ((l16 & 7) << 3)));
#pragma unroll
      for (int k = 0; k < 4; ++k) {
        acc[0][k] = __builtin_amdgcn_mfma_f32_16x16x32_bf16(Ak[k][ks], b0, acc[0][k], 0, 0, 0);
        acc[1][k] = __builtin_amdgcn_mfma_f32_16x16x32_bf16(Ak[k][ks], b1, acc[1][k], 0, 0, 0);
      }
    }
#pragma unroll
    for (int cf = 0; cf < 2; ++cf) {
      floatx4 L;
#pragma unroll
      for (int r = 0; r < 4; ++r) {
        int av = adjv[cf][r];
        float s = NEGM;
        s = (av == 1) ? acc[cf][0][r] : s;
        s = (av == 2) ? acc[cf][1][r] : s;
        s = (av == 3) ? acc[cf][2][r] : s;
        s = (av == 4) ? acc[cf][3][r] : s;
        s = (s > 0.f) ? s : LEAKY * s;
        L[r] = s;
      }
      logits[it * 2 + cf] = L;
    }
    __syncthreads();
  }

  // issue phase-2 pair 0 (HT tiles d:0..31 and d:128..159); overlaps softmax
  stage_pair(HTswB, HTswB + 4 * 32 * 256, Bbase, Bbase + 16384, w, l);

  // ---- softmax across both m-halves via LDS partials ----
  const int row0 = rw * 16 + lhi * 4;
#pragma unroll
  for (int r = 0; r < 4; ++r) {
    float m = logits[0][r];
#pragma unroll
    for (int f = 1; f < 8; ++f) m = fmaxf(m, logits[f][r]);
#pragma unroll
    for (int s = 1; s < 16; s <<= 1) m = fmaxf(m, __shfl_xor(m, s));
    if (l16 == 0) pmax[(row0 + r) * 2 + mh] = m;
  }
  __syncthreads();
#pragma unroll
  for (int r = 0; r < 4; ++r) {
    float gm = fmaxf(pmax[(row0 + r) * 2], pmax[(row0 + r) * 2 + 1]);
    float s = 0.f;
#pragma unroll
    for (int f = 0; f < 8; ++f) {
      float e = __expf(logits[f][r] - gm);
      logits[f][r] = e;
      s += e;
    }
#pragma unroll
    for (int sh = 1; sh < 16; sh <<= 1) s += __shfl_xor(s, sh);
    if (l16 == 0) psum[(row0 + r) * 2 + mh] = s;
  }
  __syncthreads();
  float inv[4];
#pragma unroll
  for (int r = 0; r < 4; ++r)
    inv[r] = 1.f / (psum[(row0 + r) * 2] + psum[(row0 + r) * 2 + 1]);
  // alpha bf16 swizzled into A-region: row, col m = mh*128 + f*16 + l16
#pragma unroll
  for (int f = 0; f < 8; ++f)
#pragma unroll
    for (int r = 0; r < 4; ++r) {
      int row = row0 + r;
      int mcol = mh * 128 + f * 16 + l16;
      ldsU[row * 256 + (mcol ^ ((row & 7) << 3))] = f2bf(logits[f][r] * inv[r]);
    }
  __syncthreads();

  // ---- Phase 2: out = alpha @ H; wave covers [16 rows][128 d (half mh)] ----
  short8 af[8];
#pragma unroll
  for (int ks = 0; ks < 8; ++ks) {
    int m0 = ks * 32 + lhi * 8;
    af[ks] = *(const short8*)(ldsU + arow * 256 + (m0 ^ ((arow & 7) << 3)));
  }
  floatx4 oa[8];
#pragma unroll
  for (int f = 0; f < 8; ++f) {
    floatx4 z = {0.f, 0.f, 0.f, 0.f};
    oa[f] = z;
  }
#pragma unroll
  for (int it = 0; it < 4; ++it) {
    const int cur = it & 1;
    if (it < 3)
      stage_pair(HTswB + (it + 1) * 32 * 256, HTswB + (it + 5) * 32 * 256,
                 Bbase + (1 - cur) * 32768, Bbase + (1 - cur) * 32768 + 16384, w, l);
    const unsigned short* Bt = (const unsigned short*)(Bbase + cur * 32768 + mh * 16384);
#pragma unroll
    for (int cf = 0; cf < 2; ++cf)
#pragma unroll
      for (int ks = 0; ks < 8; ++ks) {
        int m0 = ks * 32 + lhi * 8;
        short8 bf = *(const short8*)(Bt + (cf * 16 + l16) * 256 + (m0 ^ ((l16 & 7) << 3)));
        oa[it * 2 + cf] = __builtin_amdgcn_mfma_f32_16x16x32_bf16(af[ks], bf, oa[it * 2 + cf], 0, 0, 0);
      }
    __syncthreads();
  }

  // ---- epilogue: L2 normalize (cross d-half combine) + residual ----
  float ssq[4] = {0.f, 0.f, 0.f, 0.f};
#pragma unroll
  for (int f = 0; f < 8; ++f)
#pragma unroll
    for (int r = 0; r < 4; ++r) ssq[r] += oa[f][r] * oa[f][r];
#pragma unroll
  for (int r = 0; r < 4; ++r) {
#pragma unroll
    for (int s = 1; s < 16; s <<= 1) ssq[r] += __shfl_xor(ssq[r], s);
    if (l16 == 0) psum[(row0 + r) * 2 + mh] = ssq[r];
  }
  __syncthreads();
  float innv[4];
#pragma unroll
  for (int r = 0; r < 4; ++r) {
    float tot = psum[(row0 + r) * 2] + psum[(row0 + r) * 2 + 1];
    innv[r] = 1.f / fmaxf(sqrtf(tot), 1e-12f);
  }
  float* ob = out + b * 65536;
#pragma unroll
  for (int f = 0; f < 8; ++f)
#pragma unroll
    for (int r = 0; r < 4; ++r) {
      int n = n0 + row0 + r;
      int d = mh * 128 + f * 16 + l16;
      ob[n * 256 + d] = oa[f][r] * innv[r] + hb[n * 256 + d];
    }
}

extern "C" void kernel_launch(void* const* d_in, const int* in_sizes, int n_in,
                              void* d_out, int out_size, void* d_ws, size_t ws_size,
                              hipStream_t stream) {
  const float* h = (const float*)d_in[0];
  const int* adj = (const int*)d_in[1];
  const float* a = (const float*)d_in[2];
  float* out = (float*)d_out;
  unsigned short* Hsw = (unsigned short*)d_ws;
  unsigned short* HTsw = Hsw + 64 * 256 * 256;
  prep_kernel<<<256, 256, 0, stream>>>(h, Hsw, HTsw);
  fused_kernel<<<256, 512, 0, stream>>>(h, adj, a, out, Hsw, HTsw);
}

// Round 5
// 125.904 us; speedup vs baseline: 1.1750x; 1.1745x over previous
//
#include <hip/hip_runtime.h>

typedef __attribute__((ext_vector_type(8))) short short8;
typedef __attribute__((ext_vector_type(4))) float floatx4;

#define LEAKY 0.2f
#define NEGM -9e15f

// --- bf16 helpers (RNE, finite inputs) ---
__device__ __forceinline__ unsigned short f2bf(float f) {
  unsigned int u = __float_as_uint(f);
  u = u + 0x7FFFu + ((u >> 16) & 1u);
  return (unsigned short)(u >> 16);
}
__device__ __forceinline__ float bf2f(short s) {
  return __uint_as_float(((unsigned int)(unsigned short)s) << 16);
}

// ---------------------------------------------------------------------------
// Prep (unchanged, known-good): h fp32 -> Hsw (row-major bf16, row-XOR baked)
//                                      -> HTsw (transposed bf16, row-XOR baked)
// ---------------------------------------------------------------------------
__global__ __launch_bounds__(256) void prep_kernel(
    const float* __restrict__ h, unsigned short* __restrict__ Hsw,
    unsigned short* __restrict__ HTsw) {
  const int b = blockIdx.x >> 2, q = blockIdx.x & 3;
  const int t = threadIdx.x;
  const float* hb = h + b * 65536;
  unsigned short* Hb = Hsw + b * 65536;
  unsigned short* HTb = HTsw + b * 65536;
#pragma unroll
  for (int j = 0; j < 8; ++j) {
    int c = t + j * 256;
    int m = 64 * q + (c >> 5);
    int d0 = (c & 31) * 8;
    const float4* src = (const float4*)(hb + m * 256 + d0);
    float4 x = src[0], y = src[1];
    short8 v;
    v[0] = (short)f2bf(x.x); v[1] = (short)f2bf(x.y);
    v[2] = (short)f2bf(x.z); v[3] = (short)f2bf(x.w);
    v[4] = (short)f2bf(y.x); v[5] = (short)f2bf(y.y);
    v[6] = (short)f2bf(y.z); v[7] = (short)f2bf(y.w);
    *(short8*)(Hb + m * 256 + (d0 ^ ((m & 7) << 3))) = v;
  }
#pragma unroll
  for (int j = 0; j < 8; ++j) {
    int p = t + j * 256;
    int d = 64 * q + (p & 63);
    int m0 = (p >> 6) * 8;
    short8 v;
#pragma unroll
    for (int jj = 0; jj < 8; ++jj) v[jj] = (short)f2bf(hb[(m0 + jj) * 256 + d]);
    *(short8*)(HTb + d * 256 + (m0 ^ ((d & 7) << 3))) = v;
  }
}

// Stage a PAIR of 16 KB tiles (32 rows x 512 B each): waves 0-3 -> tile0,
// waves 4-7 -> tile1. Linear LDS dest (wave-uniform base), width=16.
__device__ __forceinline__ void stage_pair(const unsigned short* g0,
                                           const unsigned short* g1,
                                           unsigned char* s0, unsigned char* s1,
                                           int w, int l) {
  const unsigned char* gsrc = (w < 4) ? (const unsigned char*)g0 : (const unsigned char*)g1;
  unsigned char* ldst = (w < 4) ? s0 : s1;
  const int wo = (w & 3) * 4096;
#pragma unroll
  for (int i = 0; i < 4; ++i) {
    const int off = wo + i * 1024;
    __builtin_amdgcn_global_load_lds(
        (const __attribute__((address_space(1))) unsigned int*)(gsrc + off + l * 16),
        (__attribute__((address_space(3))) unsigned int*)(ldst + off), 16, 0, 0);
  }
}

// ---------------------------------------------------------------------------
// Fused v4: block = (b, 64 n-rows), 512 threads = 8 waves.
// wave w: rw = w&3 (16-row group), mh = w>>2 (m- or d-half of 128).
// Phase 1 is TWO PASSES over the m-tiles (k={0,1} then k={2,3}) so the
// per-k A-fragment array is Ak[2][8] = 64 VGPR instead of 128 (v3 kept all
// 4 k's -> ~220 live VGPR vs the compiler's 128 budget -> ~95 MB spills).
// adj is packed 8x4-bit per u32 (4 VGPR total, loaded once).
// LDS: [0,32K) A then alpha; [32K,96K) B tile-pair double buffer;
//      [96K,100K) a fp32; [100K,100.5K) pmax; [100.5K,101K) psum/psq.
// ---------------------------------------------------------------------------
__global__
__attribute__((amdgpu_flat_work_group_size(512, 512), amdgpu_waves_per_eu(2, 2)))
void fused_kernel(
    const float* __restrict__ h, const int* __restrict__ adj,
    const float* __restrict__ a, float* __restrict__ out,
    const unsigned short* __restrict__ Hsw, const unsigned short* __restrict__ HTsw) {
  __shared__ __align__(16) unsigned char lds[103424];
  unsigned short* ldsU = (unsigned short*)lds;
  unsigned char* Bbase = lds + 32768;
  float* aLds = (float*)(lds + 98304);
  float* pmax = (float*)(lds + 102400);  // [64][2]
  float* psum = (float*)(lds + 102912);  // [64][2] (reused as psq)

  const int tid = threadIdx.x;
  const int w = tid >> 6, l = tid & 63;
  const int l16 = l & 15, lhi = l >> 4;
  const int rw = w & 3, mh = w >> 2;
  // XCD swizzle: 4 blocks of same b co-resident on one XCD (grid 256)
  const int id = blockIdx.x;
  const int b = (id & 7) + 8 * (id >> 5);
  const int n0 = ((id >> 3) & 3) * 64;

  const float* hb = h + b * 65536;
  const int* adjb = adj + b * 65536;
  const unsigned short* HswB = Hsw + b * 65536;
  const unsigned short* HTswB = HTsw + b * 65536;

  // prologue: stage phase-1 pair 0 (tiles m:0..31 and m:128..159)
  stage_pair(HswB, HswB + 4 * 32 * 256, Bbase, Bbase + 16384, w, l);

  // stage A rows (n0..n0+63) straight from Hsw (already bf16 + row-swizzled;
  // n0 % 64 == 0 so baked (row&7) swizzle == local swizzle). 32 KB linear.
  {
    const unsigned char* asrc = (const unsigned char*)(HswB + n0 * 256);
#pragma unroll
    for (int i = 0; i < 4; ++i) {
      const int off = i * 8192 + w * 1024;
      __builtin_amdgcn_global_load_lds(
          (const __attribute__((address_space(1))) unsigned int*)(asrc + off + l * 16),
          (__attribute__((address_space(3))) unsigned int*)(lds + off), 16, 0, 0);
    }
  }
  if (tid < 256) ((float4*)aLds)[tid] = ((const float4*)a)[tid];

  // adj values packed 4-bit: adjp[it] nibble (cf*4+r) = adj in [0,4]
  unsigned int adjp[4] = {0u, 0u, 0u, 0u};
  {
    const int* adjrow = adjb + (n0 + rw * 16 + lhi * 4) * 256;
#pragma unroll
    for (int it = 0; it < 4; ++it)
#pragma unroll
      for (int cf = 0; cf < 2; ++cf)
#pragma unroll
        for (int r = 0; r < 4; ++r) {
          unsigned int v = (unsigned int)adjrow[r * 256 + mh * 128 + it * 32 + cf * 16 + l16];
          adjp[it] |= v << ((cf * 4 + r) * 4);
        }
  }
  __syncthreads();  // A + a + pair 0 ready (barrier drains vmcnt)

  const int arow = rw * 16 + l16;
  floatx4 logits[8];

  // ---- Phase 1: two passes (k-pair per pass) x 4 m-tile-pair iterations ----
#pragma unroll
  for (int p = 0; p < 2; ++p) {
    // build Ak for k = 2p, 2p+1 (reads A-region + aLds; both stable)
    short8 Ak[2][8];
#pragma unroll
    for (int ks = 0; ks < 8; ++ks) {
      int d0 = ks * 32 + lhi * 8;
      short8 hv = *(const short8*)(ldsU + arow * 256 + (d0 ^ ((arow & 7) << 3)));
      float hf[8];
#pragma unroll
      for (int jj = 0; jj < 8; ++jj) hf[jj] = bf2f(hv[jj]);
#pragma unroll
      for (int kk = 0; kk < 2; ++kk) {
        const float4* a4 = (const float4*)(aLds + (p * 2 + kk) * 256 + d0);
        float4 pa = a4[0], qa = a4[1];
        short8 o;
        o[0] = (short)f2bf(hf[0] * pa.x);  o[1] = (short)f2bf(hf[1] * pa.y);
        o[2] = (short)f2bf(hf[2] * pa.z);  o[3] = (short)f2bf(hf[3] * pa.w);
        o[4] = (short)f2bf(hf[4] * qa.x);  o[5] = (short)f2bf(hf[5] * qa.y);
        o[6] = (short)f2bf(hf[6] * qa.z);  o[7] = (short)f2bf(hf[7] * qa.w);
        Ak[kk][ks] = o;
      }
    }
#pragma unroll
    for (int it = 0; it < 4; ++it) {
      const int g = p * 4 + it;       // global step 0..7 over the same 4 pairs
      const int cur = g & 1;
      if (g < 7) {
        const int nt = (g + 1) & 3;
        stage_pair(HswB + nt * 32 * 256, HswB + (nt + 4) * 32 * 256,
                   Bbase + (1 - cur) * 32768, Bbase + (1 - cur) * 32768 + 16384, w, l);
      }
      floatx4 acc[2][2];
#pragma unroll
      for (int cf = 0; cf < 2; ++cf)
#pragma unroll
        for (int kk = 0; kk < 2; ++kk) {
          floatx4 z = {0.f, 0.f, 0.f, 0.f};
          acc[cf][kk] = z;
        }
      const unsigned short* Bt = (const unsigned short*)(Bbase + cur * 32768 + mh * 16384);
#pragma unroll
      for (int ks = 0; ks < 8; ++ks) {
        int d0 = ks * 32 + lhi * 8;
        short8 b0 = *(const short8*)(Bt + l16 * 256 + (d0 ^ ((l16 & 7) << 3)));
        short8 b1 = *(const short8*)(Bt + (16 + l16) * 256 + (d0 ^ ((l16 & 7) << 3)));
        acc[0][0] = __builtin_amdgcn_mfma_f32_16x16x32_bf16(Ak[0][ks], b0, acc[0][0], 0, 0, 0);
        acc[0][1] = __builtin_amdgcn_mfma_f32_16x16x32_bf16(Ak[1][ks], b0, acc[0][1], 0, 0, 0);
        acc[1][0] = __builtin_amdgcn_mfma_f32_16x16x32_bf16(Ak[0][ks], b1, acc[1][0], 0, 0, 0);
        acc[1][1] = __builtin_amdgcn_mfma_f32_16x16x32_bf16(Ak[1][ks], b1, acc[1][1], 0, 0, 0);
      }
      // incremental merge: pass p handles adj values 2p+1 and 2p+2
#pragma unroll
      for (int cf = 0; cf < 2; ++cf)
#pragma unroll
        for (int r = 0; r < 4; ++r) {
          unsigned int av = (adjp[it] >> ((cf * 4 + r) * 4)) & 15u;
          float e0 = acc[cf][0][r], e1 = acc[cf][1][r];
          float l0 = e0 > 0.f ? e0 : LEAKY * e0;
          float l1 = e1 > 0.f ? e1 : LEAKY * e1;
          float s = (p == 0) ? NEGM : logits[it * 2 + cf][r];
          s = (av == (unsigned)(p * 2 + 1)) ? l0 : s;
          s = (av == (unsigned)(p * 2 + 2)) ? l1 : s;
          logits[it * 2 + cf][r] = s;
        }
      __syncthreads();
    }
  }

  // issue phase-2 pair 0 (HT tiles d:0..31 and d:128..159); overlaps softmax
  stage_pair(HTswB, HTswB + 4 * 32 * 256, Bbase, Bbase + 16384, w, l);

  // ---- softmax across both m-halves via LDS partials ----
  const int row0 = rw * 16 + lhi * 4;
#pragma unroll
  for (int r = 0; r < 4; ++r) {
    float m = logits[0][r];
#pragma unroll
    for (int f = 1; f < 8; ++f) m = fmaxf(m, logits[f][r]);
#pragma unroll
    for (int s = 1; s < 16; s <<= 1) m = fmaxf(m, __shfl_xor(m, s));
    if (l16 == 0) pmax[(row0 + r) * 2 + mh] = m;
  }
  __syncthreads();
#pragma unroll
  for (int r = 0; r < 4; ++r) {
    float gm = fmaxf(pmax[(row0 + r) * 2], pmax[(row0 + r) * 2 + 1]);
    float s = 0.f;
#pragma unroll
    for (int f = 0; f < 8; ++f) {
      float e = __expf(logits[f][r] - gm);
      logits[f][r] = e;
      s += e;
    }
#pragma unroll
    for (int sh = 1; sh < 16; sh <<= 1) s += __shfl_xor(s, sh);
    if (l16 == 0) psum[(row0 + r) * 2 + mh] = s;
  }
  __syncthreads();
  float inv[4];
#pragma unroll
  for (int r = 0; r < 4; ++r)
    inv[r] = 1.f / (psum[(row0 + r) * 2] + psum[(row0 + r) * 2 + 1]);
  // alpha bf16 swizzled into A-region: row, col m = mh*128 + f*16 + l16
#pragma unroll
  for (int f = 0; f < 8; ++f)
#pragma unroll
    for (int r = 0; r < 4; ++r) {
      int row = row0 + r;
      int mcol = mh * 128 + f * 16 + l16;
      ldsU[row * 256 + (mcol ^ ((row & 7) << 3))] = f2bf(logits[f][r] * inv[r]);
    }
  __syncthreads();

  // ---- Phase 2: out = alpha @ H; wave covers [16 rows][128 d (half mh)] ----
  short8 af[8];
#pragma unroll
  for (int ks = 0; ks < 8; ++ks) {
    int m0 = ks * 32 + lhi * 8;
    af[ks] = *(const short8*)(ldsU + arow * 256 + (m0 ^ ((arow & 7) << 3)));
  }
  floatx4 oa[8];
#pragma unroll
  for (int f = 0; f < 8; ++f) {
    floatx4 z = {0.f, 0.f, 0.f, 0.f};
    oa[f] = z;
  }
#pragma unroll
  for (int it = 0; it < 4; ++it) {
    const int cur = it & 1;
    if (it < 3)
      stage_pair(HTswB + (it + 1) * 32 * 256, HTswB + (it + 5) * 32 * 256,
                 Bbase + (1 - cur) * 32768, Bbase + (1 - cur) * 32768 + 16384, w, l);
    const unsigned short* Bt = (const unsigned short*)(Bbase + cur * 32768 + mh * 16384);
#pragma unroll
    for (int cf = 0; cf < 2; ++cf)
#pragma unroll
      for (int ks = 0; ks < 8; ++ks) {
        int m0 = ks * 32 + lhi * 8;
        short8 bf = *(const short8*)(Bt + (cf * 16 + l16) * 256 + (m0 ^ ((l16 & 7) << 3)));
        oa[it * 2 + cf] = __builtin_amdgcn_mfma_f32_16x16x32_bf16(af[ks], bf, oa[it * 2 + cf], 0, 0, 0);
      }
    __syncthreads();
  }

  // ---- epilogue: L2 normalize (cross d-half combine) + residual ----
  float ssq[4] = {0.f, 0.f, 0.f, 0.f};
#pragma unroll
  for (int f = 0; f < 8; ++f)
#pragma unroll
    for (int r = 0; r < 4; ++r) ssq[r] += oa[f][r] * oa[f][r];
#pragma unroll
  for (int r = 0; r < 4; ++r) {
#pragma unroll
    for (int s = 1; s < 16; s <<= 1) ssq[r] += __shfl_xor(ssq[r], s);
    if (l16 == 0) psum[(row0 + r) * 2 + mh] = ssq[r];
  }
  __syncthreads();
  float innv[4];
#pragma unroll
  for (int r = 0; r < 4; ++r) {
    float tot = psum[(row0 + r) * 2] + psum[(row0 + r) * 2 + 1];
    innv[r] = 1.f / fmaxf(sqrtf(tot), 1e-12f);
  }
  float* ob = out + b * 65536;
#pragma unroll
  for (int f = 0; f < 8; ++f)
#pragma unroll
    for (int r = 0; r < 4; ++r) {
      int n = n0 + row0 + r;
      int d = mh * 128 + f * 16 + l16;
      ob[n * 256 + d] = oa[f][r] * innv[r] + hb[n * 256 + d];
    }
}

extern "C" void kernel_launch(void* const* d_in, const int* in_sizes, int n_in,
                              void* d_out, int out_size, void* d_ws, size_t ws_size,
                              hipStream_t stream) {
  const float* h = (const float*)d_in[0];
  const int* adj = (const int*)d_in[1];
  const float* a = (const float*)d_in[2];
  float* out = (float*)d_out;
  unsigned short* Hsw = (unsigned short*)d_ws;
  unsigned short* HTsw = Hsw + 64 * 256 * 256;
  prep_kernel<<<256, 256, 0, stream>>>(h, Hsw, HTsw);
  fused_kernel<<<256, 512, 0, stream>>>(h, adj, a, out, Hsw, HTsw);
}